// Round 11
// baseline (134.168 us; speedup 1.0000x reference)
//
#include <hip/hip_runtime.h>

#define BATCH 32768
#define DIM   256
#define NEXP  8
#define MT    32          // rows per tile
#define STRIDE 264        // DIM + 8 bf16 pad (measured 0 bank conflicts)
#define RANGE 1024        // samples owned per block (ownership partitioning)
#define FCAP  512         // local list capacity (Binomial(1024,1/8)~128; hard-guarded)

typedef __bf16 bf16x8 __attribute__((ext_vector_type(8)));
typedef __bf16 bf16x4 __attribute__((ext_vector_type(4)));
typedef float  f32x16 __attribute__((ext_vector_type(16)));

static __device__ __forceinline__ float sigmoid_f(float x) {
    return __builtin_amdgcn_rcpf(1.f + __expf(-x));
}
static __device__ __forceinline__ float tanh_f(float x) {
    return 1.f - 2.f * __builtin_amdgcn_rcpf(__expf(2.f * x) + 1.f);
}

// LDS-only barrier (no vmcnt drain): all cross-thread data flows through LDS;
// global loads are consumed by the issuing thread; out is never read back.
static __device__ __forceinline__ void lds_barrier() {
    asm volatile("s_waitcnt lgkmcnt(0)\n\ts_barrier" ::: "memory");
}

// ---- SINGLE-KERNEL fused MoE-MLP. R10's wave-specialized core, now fully
// self-contained (R10 accounting: memset+prep = 2 dispatch slots ~4-6us, the
// largest remaining removable item; mlp itself is scattered-HBM-BW-bound).
//
// Ownership partitioning kills the cross-block-consistency requirement that
// forced a separate scatter pass: block (e = bid>>5, s = bid&31) owns sample
// range [s*1024, s*1024+1024) and processes its expert-e samples therein
// (~128 = ~4 tiles). Each block:
//   A1. loads its role's weight fragments DIRECTLY from fp32 W1/W2 (4 MB
//       total, L2/L3-broadcast; same (__bf16) cast as the old prep),
//   A2. ballot-compacts its local index list into LDS (deterministic order,
//       block-private — no global scatter, no atomics, no workspace),
//   B.  runs the R10 pipeline: G1 waves (0-3, W1-resident) GEMM1+tanh->H;
//       G2 waves (4-7, W2-resident) GEMM2+epilogue->out and stage the next
//       y-tile issue-early/write-late; 1 lds_barrier per region; T5 setprio.
__global__ void __launch_bounds__(512, 2)
mlp_kernel(const float* __restrict__ t,
           const float* __restrict__ y,
           const float* __restrict__ scales,
           const float* __restrict__ shifta,
           const float* __restrict__ shiftb,
           const float* __restrict__ b1,
           const float* __restrict__ b2,
           const float* __restrict__ W1,
           const float* __restrict__ W2,
           float* __restrict__ out) {
    __shared__ __bf16 Y[2][MT * STRIDE];   // staged y tiles (bf16)   33.8 KB
    __shared__ __bf16 H[2][MT * STRIDE];   // tanh(h) tiles           33.8 KB
    __shared__ int flat[FCAP];             // local sample indices     2 KB
    __shared__ int wcnt[8];

    const int tx   = threadIdx.x;
    const int wave = tx >> 6;     // 0..7
    const int lane = tx & 63;
    const int nl   = lane & 31;
    const int kh   = lane >> 5;
    const bool isG1 = (wave < 4);
    const int  w    = wave & 3;        // slice-group 0..3 within role
    const int  n0   = w * 64 + nl;     // output col, slice 0
    const int  n1   = n0 + 32;         // output col, slice 1

    const int e = blockIdx.x >> 5;     // expert
    const int s = blockIdx.x & 31;     // owned sample range

    // ---- A1: role weights straight from fp32 global (L2-broadcast).
    // frag elem j (slice ss, frag ks) = W[e][(w*2+ss)*32+nl][ks*16+kh*8+j]
    const float* Wsrc = (isG1 ? W1 : W2) + (e << 16);
    bf16x8 wf[2][16];
#pragma unroll
    for (int ss = 0; ss < 2; ++ss)
#pragma unroll
        for (int ks = 0; ks < 16; ++ks) {
            const float* p = Wsrc + (((w * 2 + ss) * 32 + nl) << 8) + ks * 16 + kh * 8;
            const float4 u0 = *(const float4*)p;
            const float4 u1 = *(const float4*)(p + 4);
            bf16x8 v;
            v[0] = (__bf16)u0.x; v[1] = (__bf16)u0.y; v[2] = (__bf16)u0.z; v[3] = (__bf16)u0.w;
            v[4] = (__bf16)u1.x; v[5] = (__bf16)u1.y; v[6] = (__bf16)u1.z; v[7] = (__bf16)u1.w;
            wf[ss][ks] = v;
        }

    // ---- A2: deterministic ballot-compaction of the owned range.
    int c = 0;
#pragma unroll
    for (int h = 0; h < RANGE / 512; ++h) {
        const int i  = s * RANGE + h * 512 + tx;
        const int ei = min((int)(t[i] * 8.0f), NEXP - 1);
        const bool se = (ei == e);
        const unsigned long long m = __ballot(se);
        if (lane == 0) wcnt[wave] = __popcll(m);
        lds_barrier();
        int wbase = 0, csum = 0;
#pragma unroll
        for (int j = 0; j < 8; ++j) {
            const int v = wcnt[j];
            if (j < wave) wbase += v;
            csum += v;
        }
        if (se) {
            const int d = c + wbase + __popcll(m & ((1ull << lane) - 1));
            if (d < FCAP) flat[d] = i;
        }
        c += csum;
        lds_barrier();   // wcnt reuse + flat complete after last iter
    }
    c = min(c, FCAP);
    if (c == 0) return;                    // block-uniform
    const int nt = (c + MT - 1) >> 5;      // local tiles

    // ---- hoisted constants
    const float sa = sigmoid_f(shifta[0]);
    const float sb = sigmoid_f(shiftb[0]);
    const float k1 = 0.5f * (sb + sa);     // 0.5*(b-a), a=-sa, b=sb
    const float k2 = 0.5f * (sb - sa);     // 0.5*(a+b)
    const bool needy = (k2 != 0.0f);       // exactly 0 with given inputs
    float b1v[2], b2v[2], cc[2];
    b1v[0] = b1[(e << 8) | n0]; b1v[1] = b1[(e << 8) | n1];
    b2v[0] = b2[(e << 8) | n0]; b2v[1] = b2[(e << 8) | n1];
    cc[0]  = k1 * sigmoid_f(scales[n0]); cc[1] = k1 * sigmoid_f(scales[n1]);

    // ---- prologue: G1 stages tile 0 (HBM) while G2 sits on loaded weights
    if (isG1) {
#pragma unroll
        for (int p = 0; p < 8; ++p) {
            const int r = w * 8 + p;
            const int g = flat[min(r, c - 1)];
            const float4 v = *(const float4*)(y + (long)g * DIM + lane * 4);
            bf16x4 wv;
            wv[0] = (__bf16)v.x; wv[1] = (__bf16)v.y; wv[2] = (__bf16)v.z; wv[3] = (__bf16)v.w;
            *(bf16x4*)(&Y[0][r * STRIDE + lane * 4]) = wv;
        }
    }
    lds_barrier();

    // ---- region t: G1 computes tile t; G2 stages tile t+1 (issue-early /
    // write-late) and computes tile t-1. Buffers disjoint by parity.
    for (int tt = 0; tt <= nt; ++tt) {
        if (isG1) {
            if (tt < nt) {
                const __bf16* ap = &Y[tt & 1][nl * STRIDE + kh * 8];
                f32x16 a0v = {}, a1v = {};
                __builtin_amdgcn_s_setprio(1);
#pragma unroll
                for (int ks = 0; ks < 16; ++ks) {
                    bf16x8 a = *(const bf16x8*)(ap + ks * 16);   // 1 read, 2 MFMA
                    a0v = __builtin_amdgcn_mfma_f32_32x32x16_bf16(a, wf[0][ks], a0v, 0, 0, 0);
                    a1v = __builtin_amdgcn_mfma_f32_32x32x16_bf16(a, wf[1][ks], a1v, 0, 0, 0);
                }
                __builtin_amdgcn_s_setprio(0);
                __bf16* hb = &H[tt & 1][0];
#pragma unroll
                for (int r = 0; r < 16; ++r) {
                    const int row = (r & 3) + ((r >> 2) << 3) + (kh << 2);
                    hb[row * STRIDE + n0] = (__bf16)tanh_f(a0v[r] + b1v[0]);
                    hb[row * STRIDE + n1] = (__bf16)tanh_f(a1v[r] + b1v[1]);
                }
            }
        } else {
            // stage tile tt+1: idx from LDS flat, y loads ride under GEMM2
            const bool do_stage = (tt + 1 < nt);
            float4 vs[8];
            if (do_stage) {
                const int rbase = (tt + 1) * MT;
#pragma unroll
                for (int p = 0; p < 8; ++p) {
                    const int g = flat[min(rbase + w * 8 + p, c - 1)];
                    vs[p] = *(const float4*)(y + (long)g * DIM + lane * 4);
                }
            }
            if (tt >= 1) {
                const __bf16* ap = &H[(tt - 1) & 1][nl * STRIDE + kh * 8];
                f32x16 a0v = {}, a1v = {};
                __builtin_amdgcn_s_setprio(1);
#pragma unroll
                for (int ks = 0; ks < 16; ++ks) {
                    bf16x8 a = *(const bf16x8*)(ap + ks * 16);
                    a0v = __builtin_amdgcn_mfma_f32_32x32x16_bf16(a, wf[0][ks], a0v, 0, 0, 0);
                    a1v = __builtin_amdgcn_mfma_f32_32x32x16_bf16(a, wf[1][ks], a1v, 0, 0, 0);
                }
                __builtin_amdgcn_s_setprio(0);
                const int rbase = (tt - 1) * MT;
#pragma unroll
                for (int r = 0; r < 16; ++r) {
                    const int row = (r & 3) + ((r >> 2) << 3) + (kh << 2);
                    const int q = rbase + row;
                    if (q < c) {
                        const int g = flat[q];
                        float r0 = cc[0] * (a0v[r] + b2v[0]);
                        float r1 = cc[1] * (a1v[r] + b2v[1]);
                        if (needy) {
                            r0 += k2 * y[(long)g * DIM + n0];
                            r1 += k2 * y[(long)g * DIM + n1];
                        }
                        out[(long)g * DIM + n0] = r0;
                        out[(long)g * DIM + n1] = r1;
                    }
                }
            }
            if (do_stage) {   // write-late: precise vmcnt wait for vs here
                const int kb = tt + 1;
#pragma unroll
                for (int p = 0; p < 8; ++p) {
                    const int r = w * 8 + p;
                    const float4 v = vs[p];
                    bf16x4 wv;
                    wv[0] = (__bf16)v.x; wv[1] = (__bf16)v.y; wv[2] = (__bf16)v.z; wv[3] = (__bf16)v.w;
                    *(bf16x4*)(&Y[kb & 1][r * STRIDE + lane * 4]) = wv;
                }
            }
        }
        lds_barrier();
    }
}

extern "C" void kernel_launch(void* const* d_in, const int* in_sizes, int n_in,
                              void* d_out, int out_size, void* d_ws, size_t ws_size,
                              hipStream_t stream) {
    const float* t      = (const float*)d_in[0];
    const float* y      = (const float*)d_in[1];
    const float* W1     = (const float*)d_in[2];
    const float* b1     = (const float*)d_in[3];
    const float* W2     = (const float*)d_in[4];
    const float* b2     = (const float*)d_in[5];
    const float* scales = (const float*)d_in[6];
    const float* shifta = (const float*)d_in[7];
    const float* shiftb = (const float*)d_in[8];
    float* out = (float*)d_out;

    // ONE dispatch. No workspace, no memset, no prep.
    mlp_kernel<<<256, 512, 0, stream>>>(t, y, scales, shifta, shiftb,
                                        b1, b2, W1, W2, out);
}

// Round 13
// 122.407 us; speedup vs baseline: 1.0961x; 1.0961x over previous
//
#include <hip/hip_runtime.h>

#define BATCH 32768
#define DIM   256
#define NEXP  8
#define MT    32          // rows per tile
#define STRIDE 264        // DIM + 8 bf16 pad (measured 0 bank conflicts)
#define SLOTS 64          // blocks per expert (2 blocks/CU: the R12 lever)

typedef __bf16 bf16x8 __attribute__((ext_vector_type(8)));
typedef __bf16 bf16x4 __attribute__((ext_vector_type(4)));
typedef float  f32x16 __attribute__((ext_vector_type(16)));

static __device__ __forceinline__ float sigmoid_f(float x) {
    return __builtin_amdgcn_rcpf(1.f + __expf(-x));
}
static __device__ __forceinline__ float tanh_f(float x) {
    return 1.f - 2.f * __builtin_amdgcn_rcpf(__expf(2.f * x) + 1.f);
}

// LDS-only barrier (no vmcnt drain): all cross-thread data flows through LDS;
// global loads are consumed by the issuing thread; out is never read back.
static __device__ __forceinline__ void lds_barrier() {
    asm volatile("s_waitcnt lgkmcnt(0)\n\ts_barrier" ::: "memory");
}

// ---- fused prep (R7/R10 version: packed-coalesced weights + cursor scatter.
// R11 proved dispatch gaps ~0 and fp32-direct weight loads cost +19us, so
// the separate pack pass stays).
__global__ void prep_kernel(const float* __restrict__ W1, const float* __restrict__ W2,
                            const float* __restrict__ t,
                            bf16x8* __restrict__ W1p, bf16x8* __restrict__ W2p,
                            int* __restrict__ cursor, int* __restrict__ idxb) {
    const int b = blockIdx.x;
    if (b < 256) {
        const int tid = b * 256 + threadIdx.x;   // = e*8192 + col*32 + ks*2 + kh
        const int kh  = tid & 1;
        const int ks  = (tid >> 1) & 15;
        const int col = (tid >> 5) & 255;
        const int e   = tid >> 13;
        const long src = (long)tid * 8;          // consecutive floats -> coalesced
        const float4 a0 = *(const float4*)(W1 + src);
        const float4 a1 = *(const float4*)(W1 + src + 4);
        const float4 c0 = *(const float4*)(W2 + src);
        const float4 c1 = *(const float4*)(W2 + src + 4);
        bf16x8 w1, w2;
        w1[0] = (__bf16)a0.x; w1[1] = (__bf16)a0.y; w1[2] = (__bf16)a0.z; w1[3] = (__bf16)a0.w;
        w1[4] = (__bf16)a1.x; w1[5] = (__bf16)a1.y; w1[6] = (__bf16)a1.z; w1[7] = (__bf16)a1.w;
        w2[0] = (__bf16)c0.x; w2[1] = (__bf16)c0.y; w2[2] = (__bf16)c0.z; w2[3] = (__bf16)c0.w;
        w2[4] = (__bf16)c1.x; w2[5] = (__bf16)c1.y; w2[6] = (__bf16)c1.z; w2[7] = (__bf16)c1.w;
        const int dst = (e << 13) | ((col >> 5) << 10) | (ks << 6) | (kh << 5) | (col & 31);
        W1p[dst] = w1;
        W2p[dst] = w2;
    } else {
        __shared__ int h[NEXP], base[NEXP];
        if (threadIdx.x < NEXP) h[threadIdx.x] = 0;
        __syncthreads();
        const int i = (b - 256) * 256 + threadIdx.x;
        const int e = min((int)(t[i] * 8.0f), NEXP - 1);
        const int lr = atomicAdd(&h[e], 1);
        __syncthreads();
        if (threadIdx.x < NEXP)
            base[threadIdx.x] = atomicAdd(&cursor[threadIdx.x], h[threadIdx.x]);
        __syncthreads();
        idxb[e * BATCH + base[e] + lr] = i;
    }
}

// ---- producer-consumer wave-specialized MLP (R10 core, measured best) at
// 2 BLOCKS PER CU (grid 512, SLOTS=64 per expert). R11's accounting showed
// mlp is HBM-BW-bound at ~2.5 TB/s effective because 1 block/CU keeps loads
// in flight only ~1/3 of the time (Little's law needs ~10KB/CU outstanding
// continuously). LDS 68.2KB/block and 128 VGPR both fit 2 blocks/CU — the
// grid size was the only binder. Doubling resident blocks doubles the
// gather/store streams per CU; setprio arbitrates MFMA vs memory between
// co-resident blocks.
__global__ void __launch_bounds__(512, 2)
mlp_kernel(const float* __restrict__ y,
           const float* __restrict__ scales,
           const float* __restrict__ shifta,
           const float* __restrict__ shiftb,
           const float* __restrict__ b1,
           const float* __restrict__ b2,
           const bf16x8* __restrict__ W1p,
           const bf16x8* __restrict__ W2p,
           const int* __restrict__ cnt,
           const int* __restrict__ idxb,
           float* __restrict__ out) {
    __shared__ __bf16 Y[2][MT * STRIDE];   // staged y tiles (bf16)   16.9x2 KB
    __shared__ __bf16 H[2][MT * STRIDE];   // tanh(h) tiles           16.9x2 KB
    __shared__ int rowsb[4][MT];           // gathered row indices, 4-deep ring

    const int tx   = threadIdx.x;
    const int wave = tx >> 6;     // 0..7
    const int lane = tx & 63;
    const int nl   = lane & 31;
    const int kh   = lane >> 5;
    const bool isG1 = (wave < 4);
    const int  w    = wave & 3;        // slice-group 0..3 within role
    const int  n0   = w * 64 + nl;     // output col, slice 0
    const int  n1   = n0 + 32;         // output col, slice 1

    const int e    = blockIdx.x / SLOTS;   // expert pinned to block
    const int slot = blockIdx.x % SLOTS;
    const int ce   = cnt[e];
    const int nt_e = (ce + MT - 1) >> 5;
    if (slot >= nt_e) return;              // block-uniform
    const int nt   = ((nt_e - slot) + SLOTS - 1) / SLOTS;   // tiles for this block
    const int* idx_e = idxb + e * BATCH;

    const bf16x8* wp = (isG1 ? W1p : W2p) + (e << 13) + ((w * 2) << 10) + lane;
    bf16x8 wf[2][16];
    int gcur[8];

    // ---- prologue, role-overlapped:
    // G1: gather+stage tile 0 (HBM latency), weights issued behind it.
    // G2: weight frags (L2) + tile-1 index prefetch.
    if (isG1) {
        const int rbase = slot * MT;
        int g0[8];
#pragma unroll
        for (int p = 0; p < 8; ++p)
            g0[p] = idx_e[min(rbase + w * 8 + p, ce - 1)];
        float4 v0[8];
#pragma unroll
        for (int p = 0; p < 8; ++p)
            v0[p] = *(const float4*)(y + (long)g0[p] * DIM + lane * 4);
#pragma unroll
        for (int s = 0; s < 2; ++s)
#pragma unroll
            for (int ks = 0; ks < 16; ++ks)
                wf[s][ks] = wp[(s << 10) + (ks << 6)];
#pragma unroll
        for (int p = 0; p < 8; ++p) {
            const int r = w * 8 + p;
            if (lane == 0) rowsb[0][r] = (rbase + r < ce) ? g0[p] : -1;
            const float4 v = v0[p];
            bf16x4 wv;
            wv[0] = (__bf16)v.x; wv[1] = (__bf16)v.y; wv[2] = (__bf16)v.z; wv[3] = (__bf16)v.w;
            *(bf16x4*)(&Y[0][r * STRIDE + lane * 4]) = wv;
        }
    } else {
#pragma unroll
        for (int s = 0; s < 2; ++s)
#pragma unroll
            for (int ks = 0; ks < 16; ++ks)
                wf[s][ks] = wp[(s << 10) + (ks << 6)];
        if (nt > 1) {
            const int rb1 = (slot + SLOTS) * MT;
#pragma unroll
            for (int p = 0; p < 8; ++p)
                gcur[p] = idx_e[min(rb1 + w * 8 + p, ce - 1)];
        }
    }

    // ---- hoisted constants
    const float sa = sigmoid_f(shifta[0]);
    const float sb = sigmoid_f(shiftb[0]);
    const float k1 = 0.5f * (sb + sa);           // 0.5*(b-a), a=-sa, b=sb
    const float k2 = 0.5f * (sb - sa);           // 0.5*(a+b)
    const bool needy = (k2 != 0.0f);             // exactly 0 with given inputs
    float b1v[2], b2v[2], cc[2];
    b1v[0] = b1[(e << 8) | n0]; b1v[1] = b1[(e << 8) | n1];
    b2v[0] = b2[(e << 8) | n0]; b2v[1] = b2[(e << 8) | n1];
    cc[0]  = k1 * sigmoid_f(scales[n0]); cc[1] = k1 * sigmoid_f(scales[n1]);

    lds_barrier();

    // ---- region t: G1 computes tile t; G2 prefetches idx t+2, y-loads
    // tile t+1 (via gcur), computes tile t-1, write-late stages t+1.
    for (int t = 0; t <= nt; ++t) {
        if (isG1) {
            if (t < nt) {
                const __bf16* ap = &Y[t & 1][nl * STRIDE + kh * 8];
                f32x16 a0v = {}, a1v = {};
                __builtin_amdgcn_s_setprio(1);
#pragma unroll
                for (int ks = 0; ks < 16; ++ks) {
                    bf16x8 a = *(const bf16x8*)(ap + ks * 16);   // 1 read, 2 MFMA
                    a0v = __builtin_amdgcn_mfma_f32_32x32x16_bf16(a, wf[0][ks], a0v, 0, 0, 0);
                    a1v = __builtin_amdgcn_mfma_f32_32x32x16_bf16(a, wf[1][ks], a1v, 0, 0, 0);
                }
                __builtin_amdgcn_s_setprio(0);
                __bf16* hb = &H[t & 1][0];
#pragma unroll
                for (int r = 0; r < 16; ++r) {
                    const int row = (r & 3) + ((r >> 2) << 3) + (kh << 2);
                    hb[row * STRIDE + n0] = (__bf16)tanh_f(a0v[r] + b1v[0]);
                    hb[row * STRIDE + n1] = (__bf16)tanh_f(a1v[r] + b1v[1]);
                }
            }
        } else {
            // (1) index prefetch for tile t+2 (consumed next region)
            int gnew[8];
            if (t + 2 < nt) {
                const int rb = (slot + (t + 2) * SLOTS) * MT;
#pragma unroll
                for (int p = 0; p < 8; ++p)
                    gnew[p] = idx_e[min(rb + w * 8 + p, ce - 1)];
            }
            // (2) y loads for tile t+1 (indices already in regs — no chain)
            const bool do_stage = (t + 1 < nt);
            float4 vs[8];
            if (do_stage) {
#pragma unroll
                for (int p = 0; p < 8; ++p)
                    vs[p] = *(const float4*)(y + (long)gcur[p] * DIM + lane * 4);
            }
            // (3) compute tile t-1
            if (t >= 1) {
                const __bf16* ap = &H[(t - 1) & 1][nl * STRIDE + kh * 8];
                f32x16 a0v = {}, a1v = {};
                __builtin_amdgcn_s_setprio(1);
#pragma unroll
                for (int ks = 0; ks < 16; ++ks) {
                    bf16x8 a = *(const bf16x8*)(ap + ks * 16);
                    a0v = __builtin_amdgcn_mfma_f32_32x32x16_bf16(a, wf[0][ks], a0v, 0, 0, 0);
                    a1v = __builtin_amdgcn_mfma_f32_32x32x16_bf16(a, wf[1][ks], a1v, 0, 0, 0);
                }
                __builtin_amdgcn_s_setprio(0);
                const int* rb = rowsb[(t - 1) & 3];
#pragma unroll
                for (int r = 0; r < 16; ++r) {
                    const int row = (r & 3) + ((r >> 2) << 3) + (kh << 2);
                    const int g = rb[row];
                    if (g >= 0) {
                        float r0 = cc[0] * (a0v[r] + b2v[0]);
                        float r1 = cc[1] * (a1v[r] + b2v[1]);
                        if (needy) {
                            r0 += k2 * y[(long)g * DIM + n0];
                            r1 += k2 * y[(long)g * DIM + n1];
                        }
                        out[(long)g * DIM + n0] = r0;
                        out[(long)g * DIM + n1] = r1;
                    }
                }
            }
            // (4) write-late stage of tile t+1; advance index ring
            if (do_stage) {
                const int kb = t + 1;
                const int rbs = (slot + kb * SLOTS) * MT;
#pragma unroll
                for (int p = 0; p < 8; ++p) {
                    const int r = w * 8 + p;
                    if (lane == 0) rowsb[kb & 3][r] = (rbs + r < ce) ? gcur[p] : -1;
                    const float4 v = vs[p];
                    bf16x4 wv;
                    wv[0] = (__bf16)v.x; wv[1] = (__bf16)v.y; wv[2] = (__bf16)v.z; wv[3] = (__bf16)v.w;
                    *(bf16x4*)(&Y[kb & 1][r * STRIDE + lane * 4]) = wv;
                }
#pragma unroll
                for (int p = 0; p < 8; ++p) gcur[p] = gnew[p];
            }
        }
        lds_barrier();
    }
}

extern "C" void kernel_launch(void* const* d_in, const int* in_sizes, int n_in,
                              void* d_out, int out_size, void* d_ws, size_t ws_size,
                              hipStream_t stream) {
    const float* t      = (const float*)d_in[0];
    const float* y      = (const float*)d_in[1];
    const float* W1     = (const float*)d_in[2];
    const float* b1     = (const float*)d_in[3];
    const float* W2     = (const float*)d_in[4];
    const float* b2     = (const float*)d_in[5];
    const float* scales = (const float*)d_in[6];
    const float* shifta = (const float*)d_in[7];
    const float* shiftb = (const float*)d_in[8];
    float* out = (float*)d_out;

    char* ws = (char*)d_ws;
    int* cursor = (int*)ws;                               // [8]
    int* idxb   = (int*)(ws + 256);                       // [8][32768]
    bf16x8* W1p = (bf16x8*)(ws + 256 + NEXP * BATCH * 4); // packed 1MB
    bf16x8* W2p = W1p + 65536;

    hipMemsetAsync(cursor, 0, 32, stream);
    prep_kernel<<<384, 256, 0, stream>>>(W1, W2, t, W1p, W2p, cursor, idxb);
    // 512 expert-pinned blocks (64 per expert), 2 blocks/CU
    mlp_kernel<<<NEXP * SLOTS, 512, 0, stream>>>(y, scales, shifta, shiftb, b1, b2,
                                                 W1p, W2p, cursor, idxb, out);
}